// Round 2
// baseline (382.888 us; speedup 1.0000x reference)
//
#include <hip/hip_runtime.h>
#include <type_traits>

typedef __attribute__((ext_vector_type(8))) short bf16x8;
typedef __attribute__((ext_vector_type(4))) float f32x4;

static __device__ __forceinline__ unsigned short f2bf(float f) {
    unsigned int u = __float_as_uint(f);
    u += 0x7fffu + ((u >> 16) & 1u);
    return (unsigned short)(u >> 16);
}

// ---------------------------------------------------------------------------
// Fused transpose + f32->bf16 convert: dst[c][r] = bf16(src[r][c]). src [R][C] f32.
// ---------------------------------------------------------------------------
__global__ __launch_bounds__(256) void transpose_cvt(
    const float* __restrict__ src, unsigned short* __restrict__ dst,
    int R, int C)
{
    __shared__ unsigned short t[64 * 72];
    const int r0 = blockIdx.y * 64, c0 = blockIdx.x * 64;
    const int tid = threadIdx.x;
    #pragma unroll
    for (int i = 0; i < 4; ++i) {
        int idx = tid + i * 256;            // 1024 quads of 4 floats = 64x64
        int row = idx >> 4, seg = idx & 15;
        f32x4 v = *(const f32x4*)&src[(size_t)(r0 + row) * C + c0 + seg * 4];
        #pragma unroll
        for (int j = 0; j < 4; ++j) t[row * 72 + seg * 4 + j] = f2bf(v[j]);
    }
    __syncthreads();
    #pragma unroll
    for (int i = 0; i < 2; ++i) {
        int idx = tid + i * 256;
        int row = idx >> 3, seg = idx & 7;   // row = dst-row within tile (src col)
        uint4 tv;
        unsigned short* tmp = (unsigned short*)&tv;
        #pragma unroll
        for (int j = 0; j < 8; ++j) tmp[j] = t[(seg * 8 + j) * 72 + row];
        *(uint4*)&dst[(size_t)(c0 + row) * R + r0 + seg * 8] = tv;
    }
}

// ---------------------------------------------------------------------------
// C[M][N] = A[M][K] * B[K][N], B pre-transposed as Bt[N][K] (bf16).
// AT = float (convert during staging) or unsigned short (bf16).
// OT = float or unsigned short.  128x128 tile, 4 waves of 64x64.
// ---------------------------------------------------------------------------
template <typename AT, typename OT>
__global__ __launch_bounds__(256) void gemm_bt(
    const AT* __restrict__ A, const unsigned short* __restrict__ Bt,
    OT* __restrict__ C, int M, int N, int K)
{
    __shared__ unsigned short As[128 * 40];   // stride 40 (80 B): 2-way max -> free
    __shared__ unsigned short Bs[128 * 40];
    const int tid  = threadIdx.x;
    const int wave = tid >> 6, lane = tid & 63, quad = lane >> 4, l16 = lane & 15;
    const int wr = (wave >> 1) * 64, wc = (wave & 1) * 64;
    const int m0 = blockIdx.y * 128, n0 = blockIdx.x * 128;

    f32x4 acc[4][4];
    #pragma unroll
    for (int i = 0; i < 4; ++i)
        #pragma unroll
        for (int j = 0; j < 4; ++j) acc[i][j] = (f32x4){0.f, 0.f, 0.f, 0.f};

    for (int kt = 0; kt < K; kt += 32) {
        #pragma unroll
        for (int i = 0; i < 2; ++i) {
            int idx = tid + i * 256;
            int row = idx >> 2, seg = idx & 3;
            if constexpr (std::is_same_v<AT, float>) {
                f32x4 v0 = *(const f32x4*)&A[(size_t)(m0 + row) * K + kt + seg * 8];
                f32x4 v1 = *(const f32x4*)&A[(size_t)(m0 + row) * K + kt + seg * 8 + 4];
                uint4 packed;
                unsigned short* p = (unsigned short*)&packed;
                #pragma unroll
                for (int j = 0; j < 4; ++j) { p[j] = f2bf(v0[j]); p[j + 4] = f2bf(v1[j]); }
                *(uint4*)&As[row * 40 + seg * 8] = packed;
            } else {
                *(uint4*)&As[row * 40 + seg * 8] =
                    *(const uint4*)&A[(size_t)(m0 + row) * K + kt + seg * 8];
            }
            *(uint4*)&Bs[row * 40 + seg * 8] =
                *(const uint4*)&Bt[(size_t)(n0 + row) * K + kt + seg * 8];
        }
        __syncthreads();
        bf16x8 af[4], bf[4];
        #pragma unroll
        for (int i = 0; i < 4; ++i) {
            af[i] = *(const bf16x8*)&As[(wr + i * 16 + l16) * 40 + quad * 8];
            bf[i] = *(const bf16x8*)&Bs[(wc + i * 16 + l16) * 40 + quad * 8];
        }
        #pragma unroll
        for (int mi = 0; mi < 4; ++mi)
            #pragma unroll
            for (int ni = 0; ni < 4; ++ni)
                acc[mi][ni] = __builtin_amdgcn_mfma_f32_16x16x32_bf16(
                    af[mi], bf[ni], acc[mi][ni], 0, 0, 0);
        __syncthreads();
    }
    #pragma unroll
    for (int mi = 0; mi < 4; ++mi)
        #pragma unroll
        for (int ni = 0; ni < 4; ++ni)
            #pragma unroll
            for (int r = 0; r < 4; ++r) {
                int row = m0 + wr + mi * 16 + quad * 4 + r;   // C/D: row=(lane>>4)*4+reg
                int col = n0 + wc + ni * 16 + l16;            //      col=lane&15
                if constexpr (std::is_same_v<OT, float>)
                    C[(size_t)row * N + col] = acc[mi][ni][r];
                else
                    C[(size_t)row * N + col] = f2bf(acc[mi][ni][r]);
            }
}

// ---------------------------------------------------------------------------
// Dual-score causal flash attention.
// grid = (32 q-tiles, 32 b*h).  Block: 4 waves, each owns 16 queries.
// qkv (bf16 ws) layout: [B*L][3072] (q | k | v), head h at cols h*64.
// q_g / k_g are f32 inputs, converted inline.
// ---------------------------------------------------------------------------
__global__ __launch_bounds__(256) void attn_kernel(
    const unsigned short* __restrict__ qkv, const float* __restrict__ qg_in,
    const float* __restrict__ kg_in, unsigned short* __restrict__ y)
{
    const int L = 2048, D3 = 3072, Dm = 1024;
    const float SC = 0.125f / 7.6246189861593985f;   // scale / (ln(2048)*T)

    const int qt = (int)gridDim.x - 1 - (int)blockIdx.x;   // long blocks dispatch first
    const int bh = blockIdx.y;
    const int b = bh >> 4, h = bh & 15;
    const int tid  = threadIdx.x;
    const int wave = tid >> 6, lane = tid & 63, quad = lane >> 4, l16 = lane & 15;

    __shared__ unsigned short K_lds[64 * 72];
    __shared__ unsigned short G_lds[64 * 72];
    __shared__ unsigned short Vt_lds[64 * 72];     // [hd][key]
    __shared__ unsigned short P_lds[4][16 * 72];   // per-wave P round-trip

    // Q (bf16) / Qg (f32->bf16) fragments: A-operand m = l16, k = c*32 + quad*8 + j
    bf16x8 qf[2], gf[2];
    {
        const int qrow = qt * 64 + wave * 16 + l16;
        const unsigned short* qp = qkv + (size_t)(b * L + qrow) * D3 + h * 64;
        const float*          gp = qg_in + (size_t)(b * L + qrow) * Dm + h * 64;
        #pragma unroll
        for (int c = 0; c < 2; ++c) {
            qf[c] = *(const bf16x8*)(qp + c * 32 + quad * 8);
            f32x4 g0 = *(const f32x4*)(gp + c * 32 + quad * 8);
            f32x4 g1 = *(const f32x4*)(gp + c * 32 + quad * 8 + 4);
            unsigned short gt[8];
            #pragma unroll
            for (int j = 0; j < 4; ++j) { gt[j] = f2bf(g0[j]); gt[j + 4] = f2bf(g1[j]); }
            gf[c] = *(const bf16x8*)gt;
        }
    }

    f32x4 o[4];
    #pragma unroll
    for (int i = 0; i < 4; ++i) o[i] = (f32x4){0.f, 0.f, 0.f, 0.f};
    float m_i[4], l_i[4];
    #pragma unroll
    for (int r = 0; r < 4; ++r) { m_i[r] = -INFINITY; l_i[r] = 0.f; }

    for (int kt = 0; kt <= qt; ++kt) {
        // ---- stage K (bf16), Kg (f32->bf16), V transposed (64 keys x 64 hd) ----
        #pragma unroll
        for (int i = 0; i < 2; ++i) {
            int idx = tid + i * 256;
            int row = idx >> 3, seg = idx & 7;
            size_t gbase = (size_t)(b * L + kt * 64 + row);
            *(uint4*)&K_lds[row * 72 + seg * 8] =
                *(const uint4*)&qkv[gbase * D3 + 1024 + h * 64 + seg * 8];
            {
                f32x4 a0 = *(const f32x4*)&kg_in[gbase * Dm + h * 64 + seg * 8];
                f32x4 a1 = *(const f32x4*)&kg_in[gbase * Dm + h * 64 + seg * 8 + 4];
                uint4 packed;
                unsigned short* p = (unsigned short*)&packed;
                #pragma unroll
                for (int j = 0; j < 4; ++j) { p[j] = f2bf(a0[j]); p[j + 4] = f2bf(a1[j]); }
                *(uint4*)&G_lds[row * 72 + seg * 8] = packed;
            }
            uint4 vv = *(const uint4*)&qkv[gbase * D3 + 2048 + h * 64 + seg * 8];
            const unsigned short* pv = (const unsigned short*)&vv;
            #pragma unroll
            for (int j = 0; j < 8; ++j)
                Vt_lds[(seg * 8 + j) * 72 + row] = pv[j];
        }
        __syncthreads();

        // ---- S = Q*K^T + Qg*Kg^T  (wave's 16 q-rows x 64 keys) ----
        f32x4 s[4];
        #pragma unroll
        for (int ni = 0; ni < 4; ++ni) {
            f32x4 a = (f32x4){0.f, 0.f, 0.f, 0.f};
            #pragma unroll
            for (int c = 0; c < 2; ++c) {
                bf16x8 kf = *(const bf16x8*)&K_lds[(ni * 16 + l16) * 72 + c * 32 + quad * 8];
                a = __builtin_amdgcn_mfma_f32_16x16x32_bf16(qf[c], kf, a, 0, 0, 0);
                bf16x8 gb = *(const bf16x8*)&G_lds[(ni * 16 + l16) * 72 + c * 32 + quad * 8];
                a = __builtin_amdgcn_mfma_f32_16x16x32_bf16(gf[c], gb, a, 0, 0, 0);
            }
            s[ni] = a;
        }

        // ---- scale + causal mask + online softmax ----
        const bool diag = (kt == qt);
        float sv[4][4];
        #pragma unroll
        for (int ni = 0; ni < 4; ++ni)
            #pragma unroll
            for (int r = 0; r < 4; ++r) {
                float v = s[ni][r] * SC;
                if (diag && (ni * 16 + l16) > (wave * 16 + quad * 4 + r)) v = -INFINITY;
                sv[ni][r] = v;
            }
        #pragma unroll
        for (int r = 0; r < 4; ++r) {
            float mx = fmaxf(fmaxf(sv[0][r], sv[1][r]), fmaxf(sv[2][r], sv[3][r]));
            #pragma unroll
            for (int off = 1; off < 16; off <<= 1) mx = fmaxf(mx, __shfl_xor(mx, off));
            float mn    = fmaxf(m_i[r], mx);
            float alpha = __expf(m_i[r] - mn);
            float rs = 0.f;
            #pragma unroll
            for (int ni = 0; ni < 4; ++ni) {
                float e = __expf(sv[ni][r] - mn);
                P_lds[wave][(quad * 4 + r) * 72 + ni * 16 + l16] = f2bf(e);
                rs += e;
            }
            #pragma unroll
            for (int off = 1; off < 16; off <<= 1) rs += __shfl_xor(rs, off);
            l_i[r] = l_i[r] * alpha + rs;
            m_i[r] = mn;
            #pragma unroll
            for (int nd = 0; nd < 4; ++nd) o[nd][r] = o[nd][r] * alpha;
        }
        asm volatile("s_waitcnt lgkmcnt(0)" ::: "memory");   // P writes -> P reads (same wave)

        // ---- O += P * V ----
        bf16x8 pa[2];
        #pragma unroll
        for (int c = 0; c < 2; ++c)
            pa[c] = *(const bf16x8*)&P_lds[wave][l16 * 72 + c * 32 + quad * 8];
        #pragma unroll
        for (int nd = 0; nd < 4; ++nd)
            #pragma unroll
            for (int c = 0; c < 2; ++c) {
                bf16x8 vf = *(const bf16x8*)&Vt_lds[(nd * 16 + l16) * 72 + c * 32 + quad * 8];
                o[nd] = __builtin_amdgcn_mfma_f32_16x16x32_bf16(pa[c], vf, o[nd], 0, 0, 0);
            }
        __syncthreads();
    }

    // ---- normalize + write y (bf16 ws) [B*L][1024] ----
    #pragma unroll
    for (int r = 0; r < 4; ++r) {
        float inv = 1.f / l_i[r];
        int row = b * L + qt * 64 + wave * 16 + quad * 4 + r;
        #pragma unroll
        for (int nd = 0; nd < 4; ++nd)
            y[(size_t)row * Dm + h * 64 + nd * 16 + l16] = f2bf(o[nd][r] * inv);
    }
}

// ---------------------------------------------------------------------------
extern "C" void kernel_launch(void* const* d_in, const int* in_sizes, int n_in,
                              void* d_out, int out_size, void* d_ws, size_t ws_size,
                              hipStream_t stream) {
    const float* x     = (const float*)d_in[0];
    const float* q_g   = (const float*)d_in[1];
    const float* k_g   = (const float*)d_in[2];
    const float* W_qkv = (const float*)d_in[3];
    const float* W_out = (const float*)d_in[4];
    float* out = (float*)d_out;
    unsigned short* ws = (unsigned short*)d_ws;

    unsigned short* qkv_ws = ws;                       // [4096][3072] bf16
    unsigned short* y_ws   = ws + 12582912;            // [4096][1024] bf16
    unsigned short* wtq    = ws + 16777216;            // [3072][1024] bf16  W_qkv^T
    unsigned short* wto    = ws + 19922944;            // [1024][1024] bf16  W_out^T

    dim3 blk(256);
    transpose_cvt<<<dim3(48, 16), blk, 0, stream>>>(W_qkv, wtq, 1024, 3072);
    transpose_cvt<<<dim3(16, 16), blk, 0, stream>>>(W_out, wto, 1024, 1024);
    gemm_bt<float, unsigned short><<<dim3(24, 32), blk, 0, stream>>>(
        x, wtq, qkv_ws, 4096, 3072, 1024);
    attn_kernel<<<dim3(32, 32), blk, 0, stream>>>(qkv_ws, q_g, k_g, y_ws);
    gemm_bt<unsigned short, float><<<dim3(8, 32), blk, 0, stream>>>(
        y_ws, wto, out, 4096, 1024, 1024);
}